// Round 2
// baseline (998.493 us; speedup 1.0000x reference)
//
#include <hip/hip_runtime.h>
#include <math.h>

// Dynamic_Loss on MI355X — round 2.
// Shapes: logit/ema_prob [8,20,512,512] f32, real_labels [8,512,512] i32,
// ema_thresh/moving_prob_avg [20] f32. Output: scalar f32.
//
// loss = sum_c (1-new_mpa[c]) * Lsum[c] / n_valid  — one streaming pass
// accumulates 61 scalars; the LAST block finishes (no second kernel).
// ws floats: [0..19] score sums, [20..39] counts, [40..59] loss sums,
// [60] valid count, [61] (as uint) completion counter.
//
// R2 change vs R1: 2 px/thread + full-channel register prefetch (20 float2
// loads issued back-to-back => 10 KB in flight per wave) to fix the
// latency-bound profile (VALUBusy 20%, HBM 17%).

#define PASTC 15
#define NCC   20
#define IGN   255
#define HW2   262144          // 512*512 = 2^18
#define ALPHAF 0.99f

__global__ __launch_bounds__(256) void dl_main(
    const float* __restrict__ logit,
    const float* __restrict__ ema,
    const float* __restrict__ thresh,
    const int*   __restrict__ real,
    const float* __restrict__ mpa,
    float*       __restrict__ ws,
    float*       __restrict__ out)
{
    __shared__ float s_acc[61];
    const int tid = threadIdx.x;
    if (tid < 61) s_acc[tid] = 0.0f;
    __syncthreads();

    const int t  = blockIdx.x * 256 + tid;
    const int p0 = t << 1;                       // 2 pixels per thread
    const int b  = p0 >> 18;                     // batch
    const int s  = p0 & (HW2 - 1);               // spatial offset
    const size_t base = (((size_t)(b * NCC)) << 18) + (size_t)s;

    const int2 rl2 = *reinterpret_cast<const int2*>(real + p0);
    const int rl[2] = {rl2.x, rl2.y};

    // Capture channel for the score/eidx gather:
    //   real==255 -> channel 0; real in [15,19] -> channel real;
    //   real<15   -> -1 meaning "use argmax value" (gather == running max).
    int cap_ch[2];
#pragma unroll
    for (int j = 0; j < 2; ++j)
        cap_ch[j] = (rl[j] == IGN) ? 0 : (rl[j] >= PASTC ? rl[j] : -1);

    // ---------- EMA pass ----------
    // Prefetch ALL channels first so the compiler issues 20 loads back-to-back.
    float2 ev[NCC];
#pragma unroll
    for (int c = 0; c < NCC; ++c)
        ev[c] = *reinterpret_cast<const float2*>(ema + base + ((size_t)c << 18));

    float e_m15[2] = {-INFINITY, -INFINITY};
    float e_cap[2] = {0.0f, 0.0f};
    int   e_arg[2] = {0, 0};
#pragma unroll
    for (int c = 0; c < NCC; ++c) {
        const float vv[2] = {ev[c].x, ev[c].y};
#pragma unroll
        for (int j = 0; j < 2; ++j) {
            if (c < PASTC && vv[j] > e_m15[j]) { e_m15[j] = vv[j]; e_arg[j] = c; }
            if (c == cap_ch[j]) e_cap[j] = vv[j];
        }
    }

    int cidx[2];   // ema class for valid pixels, -1 otherwise
#pragma unroll
    for (int j = 0; j < 2; ++j) {
        const int   el  = (rl[j] >= PASTC) ? rl[j] : e_arg[j];       // 255 stays 255
        const float esc = (cap_ch[j] >= 0) ? e_cap[j] : e_m15[j];    // exact stored prob
        const float th  = thresh[el < NCC ? el : (NCC - 1)];
        const bool  valid = (el < NCC) && (esc >= th);
        cidx[j] = valid ? el : -1;
    }

    // ---------- logit pass ----------
    float2 lv[NCC];
#pragma unroll
    for (int c = 0; c < NCC; ++c)
        lv[c] = *reinterpret_cast<const float2*>(logit + base + ((size_t)c << 18));

    float m20[2]  = {-INFINITY, -INFINITY};
    float se[2]   = {0.0f, 0.0f};
    float m15[2]  = {-INFINITY, -INFINITY};
    float capS[2] = {0.0f, 0.0f};
    float capL[2] = {0.0f, 0.0f};
    int   arg15[2] = {0, 0};

#pragma unroll
    for (int c = 0; c < NCC; ++c) {
        const float vv[2] = {lv[c].x, lv[c].y};
#pragma unroll
        for (int j = 0; j < 2; ++j) {
            const float x  = vv[j];
            const float mo = m20[j];
            // one exp/channel online softmax: e = exp(-|x-m|)
            const float e  = __expf(-fabsf(x - mo));
            const bool  g  = x > mo;
            se[j]  = g ? fmaf(se[j], e, 1.0f) : (se[j] + e);
            m20[j] = fmaxf(mo, x);
            if (c < PASTC && x > m15[j]) { m15[j] = x; arg15[j] = c; }
            if (c == cap_ch[j]) capS[j] = x;
            if (c == cidx[j])   capL[j] = x;
        }
    }

    // ---------- per-pixel epilogue -> LDS bins ----------
#pragma unroll
    for (int j = 0; j < 2; ++j) {
        const float lse = m20[j] + __logf(se[j]);
        if (rl[j] != IGN) {
            const int   lab  = (rl[j] >= PASTC) ? rl[j] : arg15[j];   // in [0,19]
            const float sval = (cap_ch[j] >= 0) ? capS[j] : m15[j];
            const float prob = __expf(sval - lse);
            atomicAdd(&s_acc[lab], prob);
            atomicAdd(&s_acc[20 + lab], 1.0f);
        }
        if (cidx[j] >= 0) {
            atomicAdd(&s_acc[40 + cidx[j]], lse - capL[j]);
        }
        // valid count: one LDS atomic per wave via ballot
        const unsigned long long bm = __ballot(cidx[j] >= 0);
        if ((tid & 63) == 0) atomicAdd(&s_acc[60], (float)__popcll(bm));
    }

    __syncthreads();
    if (tid < 61) atomicAdd(&ws[tid], s_acc[tid]);

    // ---------- last-block finalize (replaces second kernel) ----------
    __threadfence();          // bin atomics globally visible before counter bump
    __syncthreads();          // all lanes' atomics issued+complete
    if (tid == 0) {
        unsigned* ctr = reinterpret_cast<unsigned*>(ws) + 61;
        const unsigned prev = atomicAdd(ctr, 1u);
        if (prev == gridDim.x - 1) {
            // coherent readback across XCDs via atomic RMW (add 0)
            float acc = 0.0f;
            for (int c = 0; c < NCC; ++c) {
                const float ssum = atomicAdd(&ws[c], 0.0f);
                const float cnt  = atomicAdd(&ws[20 + c], 0.0f);
                const float lsum = atomicAdd(&ws[40 + c], 0.0f);
                const float m    = mpa[c];
                const float mean = ssum / fmaxf(cnt, 1.0f);
                const float nm   = (cnt > 0.0f)
                                     ? ((m == -1.0f) ? mean
                                                     : (1.0f - ALPHAF) * mean + ALPHAF * m)
                                     : m;
                acc += lsum * (1.0f - nm);
            }
            out[0] = acc / atomicAdd(&ws[60], 0.0f);
        }
    }
}

extern "C" void kernel_launch(void* const* d_in, const int* in_sizes, int n_in,
                              void* d_out, int out_size, void* d_ws, size_t ws_size,
                              hipStream_t stream) {
    const float* logit  = (const float*)d_in[0];
    const float* ema    = (const float*)d_in[1];
    const float* thresh = (const float*)d_in[2];
    const int*   real   = (const int*)d_in[3];
    const float* mpa    = (const float*)d_in[4];
    float* out = (float*)d_out;
    float* ws  = (float*)d_ws;

    // ws is re-poisoned to 0xAA before every timed launch; zero bins + counter.
    hipMemsetAsync(ws, 0, 64 * sizeof(float), stream);

    // 2,097,152 pixels / 2 per thread / 256 per block = 4096 blocks (exact)
    dl_main<<<4096, 256, 0, stream>>>(logit, ema, thresh, real, mpa, ws, out);
}

// Round 3
// 450.504 us; speedup vs baseline: 2.2164x; 2.2164x over previous
//
#include <hip/hip_runtime.h>
#include <math.h>

// Dynamic_Loss on MI355X — round 3.
// Shapes: logit/ema_prob [8,20,512,512] f32, real_labels [8,512,512] i32,
// ema_thresh/moving_prob_avg [20] f32. Output: scalar f32.
//
// loss = sum_c (1-new_mpa[c]) * Lsum[c] / n_valid — one streaming pass
// accumulates 61 scalars in ws; tiny dl_final finishes.
// ws floats: [0..19] score sums, [20..39] counts, [40..59] loss sums, [60] valid count.
//
// R3 vs R1: 1 px/thread (shorter chains, <=64 VGPR -> 8 waves/SIMD), fused
// ema+logit channel loop (2x MLP), explicit 5-channel prefetch double-buffer.
// R2's per-block __threadfence finalize REMOVED (L2-invalidate storm, 5.5x loss).

#define PASTC 15
#define NCC   20
#define IGN   255
#define HW2   262144          // 512*512 = 2^18
#define ALPHAF 0.99f

__global__ __launch_bounds__(256, 8) void dl_main(
    const float* __restrict__ logit,
    const float* __restrict__ ema,
    const float* __restrict__ thresh,
    const int*   __restrict__ real,
    float*       __restrict__ ws)
{
    __shared__ float s_acc[61];
    const int tid = threadIdx.x;
    if (tid < 61) s_acc[tid] = 0.0f;
    __syncthreads();

    const int t = blockIdx.x * 256 + tid;          // one pixel per thread
    const int b = t >> 18;                         // batch
    const int s = t & (HW2 - 1);                   // spatial offset
    const size_t base = (((size_t)(b * NCC)) << 18) + (size_t)s;

    const int rl = real[t];
    // Gather channel known up-front:
    //   rl==255 -> ch 0; rl in [15,19] -> ch rl; rl<15 -> -1 (use argmax value).
    const int cap_ch = (rl == IGN) ? 0 : (rl >= PASTC ? rl : -1);

    // running state
    float e_m15 = -INFINITY, e_cap = 0.0f;
    int   e_arg = 0;
    float m20 = -INFINITY, se = 0.0f, m15 = -INFINITY, capS = 0.0f;
    int   arg15 = 0;

    // ---------- fused channel loop: groups of 5, prefetch next group ----------
    float ecur[5], lcur[5];
#pragma unroll
    for (int i = 0; i < 5; ++i) {
        ecur[i] = ema  [base + ((size_t)i << 18)];
        lcur[i] = logit[base + ((size_t)i << 18)];
    }

#pragma unroll
    for (int g = 0; g < 4; ++g) {
        float enxt[5], lnxt[5];
        if (g < 3) {
#pragma unroll
            for (int i = 0; i < 5; ++i) {
                enxt[i] = ema  [base + ((size_t)(g * 5 + 5 + i) << 18)];
                lnxt[i] = logit[base + ((size_t)(g * 5 + 5 + i) << 18)];
            }
        }
#pragma unroll
        for (int i = 0; i < 5; ++i) {
            const int   c = g * 5 + i;
            const float e = ecur[i];
            const float x = lcur[i];
            // EMA reductions
            if (c < PASTC && e > e_m15) { e_m15 = e; e_arg = c; }
            if (c == cap_ch) e_cap = e;
            // online softmax over logits (one exp/channel)
            const float mo = m20;
            const float ex = __expf(-fabsf(x - mo));
            se  = (x > mo) ? fmaf(se, ex, 1.0f) : (se + ex);
            m20 = fmaxf(mo, x);
            if (c < PASTC && x > m15) { m15 = x; arg15 = c; }
            if (c == cap_ch) capS = x;
        }
        if (g < 3) {
#pragma unroll
            for (int i = 0; i < 5; ++i) { ecur[i] = enxt[i]; lcur[i] = lnxt[i]; }
        }
    }

    // ---------- per-pixel epilogue ----------
    const int   el    = (rl >= PASTC) ? rl : e_arg;            // 255 stays 255
    const float esc   = (cap_ch >= 0) ? e_cap : e_m15;         // exact stored prob
    const float th    = thresh[el < NCC ? el : (NCC - 1)];
    const bool  valid = (el < NCC) && (esc >= th);
    const int   cidx  = valid ? el : -1;

    const float lse = m20 + __logf(se);

    if (rl != IGN) {
        const int   lab  = (rl >= PASTC) ? rl : arg15;         // in [0,19]
        const float sval = (cap_ch >= 0) ? capS : m15;
        const float prob = __expf(sval - lse);
        atomicAdd(&s_acc[lab], prob);
        atomicAdd(&s_acc[20 + lab], 1.0f);
    }
    if (cidx >= 0) {
        // logit value at the (post-loop-known) ema class: re-load, hits L2
        const float capL = logit[base + ((size_t)cidx << 18)];
        atomicAdd(&s_acc[40 + cidx], lse - capL);
    }
    // valid count: one LDS atomic per wave via ballot
    const unsigned long long bm = __ballot(cidx >= 0);
    if ((tid & 63) == 0) atomicAdd(&s_acc[60], (float)__popcll(bm));

    __syncthreads();
    if (tid < 61) atomicAdd(&ws[tid], s_acc[tid]);
}

__global__ void dl_final(const float* __restrict__ ws,
                         const float* __restrict__ mpa,
                         float*       __restrict__ out)
{
    if (threadIdx.x == 0 && blockIdx.x == 0) {
        float acc = 0.0f;
        for (int c = 0; c < NCC; ++c) {
            const float ssum = ws[c];
            const float cnt  = ws[20 + c];
            const float lsum = ws[40 + c];
            const float m    = mpa[c];
            const float mean = ssum / fmaxf(cnt, 1.0f);
            const float nm   = (cnt > 0.0f)
                                 ? ((m == -1.0f) ? mean
                                                 : (1.0f - ALPHAF) * mean + ALPHAF * m)
                                 : m;
            acc += lsum * (1.0f - nm);
        }
        out[0] = acc / ws[60];
    }
}

extern "C" void kernel_launch(void* const* d_in, const int* in_sizes, int n_in,
                              void* d_out, int out_size, void* d_ws, size_t ws_size,
                              hipStream_t stream) {
    const float* logit  = (const float*)d_in[0];
    const float* ema    = (const float*)d_in[1];
    const float* thresh = (const float*)d_in[2];
    const int*   real   = (const int*)d_in[3];
    const float* mpa    = (const float*)d_in[4];
    float* out = (float*)d_out;
    float* ws  = (float*)d_ws;

    // ws is re-poisoned to 0xAA before every timed launch; zero the 61 bins.
    hipMemsetAsync(ws, 0, 64 * sizeof(float), stream);

    // 2,097,152 pixels / 1 per thread / 256 per block = 8192 blocks (exact)
    dl_main<<<8192, 256, 0, stream>>>(logit, ema, thresh, real, ws);
    dl_final<<<1, 64, 0, stream>>>(ws, mpa, out);
}

// Round 4
// 367.512 us; speedup vs baseline: 2.7169x; 1.2258x over previous
//
#include <hip/hip_runtime.h>
#include <math.h>

// Dynamic_Loss on MI355X — round 4.
// Shapes: logit/ema_prob [8,20,512,512] f32, real_labels [8,512,512] i32,
// ema_thresh/moving_prob_avg [20] f32. Output: scalar f32.
//
// loss = sum_c (1-new_mpa[c]) * Lsum[c] / n_valid — streaming pass -> 61 bins
// in ws; tiny dl_final finishes. ws floats: [0..19] score sums, [20..39]
// counts, [40..59] loss sums, [60] valid count.
//
// R4: register-prefetch attempts (R2/R3) were defeated by the register
// allocator (VGPR 52/28 -> serialized loads, latency-bound, 3-11% VALU).
// Switch to async DMA staging: __builtin_amdgcn_global_load_lds width=16,
// 40 KB/tile (256 px x 40 channel-rows), 40 wave-instrs/tile, barrier,
// compute from LDS (ds_read_b32, 2-way bank alias = free). DMA holds a full
// tile in flight per block with ZERO VGPR cost -> compiler can't sink it.
// 3 blocks/CU co-resident cover each other's barrier drains.

#define PASTC 15
#define NCC   20
#define IGN   255
#define HW2   262144          // 512*512 = 2^18
#define ALPHAF 0.99f

#define TPX   256             // pixels per tile
#define NBLK  1024            // persistent blocks (4/CU requested, 3 fit by LDS)
#define ITER  8               // 2^21 px / 256 px / 1024 blocks

typedef const __attribute__((address_space(1))) void* gp1_t;
typedef __attribute__((address_space(3))) void*       sp3_t;

__global__ __launch_bounds__(256) void dl_main(
    const float* __restrict__ logit,
    const float* __restrict__ ema,
    const float* __restrict__ thresh,
    const int*   __restrict__ real,
    float*       __restrict__ ws)
{
    // stage: rows 0..19 = logit ch, rows 20..39 = ema ch, each row 256 px.
    __shared__ float stage[40 * TPX];     // 40 KB
    __shared__ float s_acc[61];

    const int tid = threadIdx.x;
    const int wv  = tid >> 6;
    const int ln  = tid & 63;
    if (tid < 61) s_acc[tid] = 0.0f;      // ordered before use by barrier below

    for (int it = 0; it < ITER; ++it) {
        const int tile = blockIdx.x * ITER + it;
        const int p0   = tile * TPX;          // tile never crosses a batch
        const int b    = p0 >> 18;
        const int s0   = p0 & (HW2 - 1);
        const size_t cb = ((size_t)(b * NCC) << 18) + (size_t)s0;

        // ---- stage tile: wave wv copies channel-rows 10*wv .. 10*wv+9 ----
        // one width-16 DMA per row: lane i -> 16 B, LDS dst = row base + i*16
#pragma unroll
        for (int k = 0; k < 10; ++k) {
            const int e  = wv * 10 + k;
            const int tn = (e >= NCC);                 // 0=logit, 1=ema
            const int ch = tn ? (e - NCC) : e;
            const float* src = (tn ? ema : logit) + cb + ((size_t)ch << 18)
                             + (size_t)ln * 4;         // 4 floats per lane
            __builtin_amdgcn_global_load_lds((gp1_t)src, (sp3_t)&stage[e * TPX],
                                             16, 0, 0);
        }
        const int rl = real[p0 + tid];

        __syncthreads();   // drains vmcnt -> all 40 rows + rl ready

        // ---- compute; thread tid owns pixel p0+tid ----
        const float* le = &stage[NCC * TPX];           // ema rows

        // EMA: argmax over first 15 channels
        float e_m15 = le[tid]; int e_arg = 0;
#pragma unroll
        for (int c = 1; c < PASTC; ++c) {
            const float v = le[c * TPX + tid];
            if (v > e_m15) { e_m15 = v; e_arg = c; }
        }
        const int   el  = (rl >= PASTC) ? rl : e_arg;            // 255 stays 255
        const float esc = (rl == IGN) ? le[tid]
                        : ((rl >= PASTC) ? le[rl * TPX + tid] : e_m15);
        const float th  = thresh[el < NCC ? el : (NCC - 1)];
        const bool  valid = (el < NCC) && (esc >= th);
        const int   cidx  = valid ? el : -1;

        // logit: max over 20 + argmax over first 15 (pass 1), sumexp (pass 2)
        float m20 = stage[tid], m15 = stage[tid]; int arg15 = 0;
#pragma unroll
        for (int c = 1; c < NCC; ++c) {
            const float v = stage[c * TPX + tid];
            if (c < PASTC && v > m15) { m15 = v; arg15 = c; }
            m20 = fmaxf(m20, v);
        }
        float se = 0.0f;
#pragma unroll
        for (int c = 0; c < NCC; ++c)
            se += __expf(stage[c * TPX + tid] - m20);
        const float lse = m20 + __logf(se);

        if (rl != IGN) {
            const int   lab  = (rl >= PASTC) ? rl : arg15;       // in [0,19]
            const float sval = (rl >= PASTC) ? stage[rl * TPX + tid] : m15;
            const float prob = __expf(sval - lse);
            atomicAdd(&s_acc[lab], prob);
            atomicAdd(&s_acc[20 + lab], 1.0f);
        }
        if (cidx >= 0) {
            const float capL = stage[cidx * TPX + tid];          // free gather
            atomicAdd(&s_acc[40 + cidx], lse - capL);
        }
        const unsigned long long bm = __ballot(cidx >= 0);
        if (ln == 0) atomicAdd(&s_acc[60], (float)__popcll(bm));

        __syncthreads();   // all reads done before next tile overwrites stage
    }

    if (tid < 61) atomicAdd(&ws[tid], s_acc[tid]);
}

__global__ void dl_final(const float* __restrict__ ws,
                         const float* __restrict__ mpa,
                         float*       __restrict__ out)
{
    if (threadIdx.x == 0 && blockIdx.x == 0) {
        float acc = 0.0f;
        for (int c = 0; c < NCC; ++c) {
            const float ssum = ws[c];
            const float cnt  = ws[20 + c];
            const float lsum = ws[40 + c];
            const float m    = mpa[c];
            const float mean = ssum / fmaxf(cnt, 1.0f);
            const float nm   = (cnt > 0.0f)
                                 ? ((m == -1.0f) ? mean
                                                 : (1.0f - ALPHAF) * mean + ALPHAF * m)
                                 : m;
            acc += lsum * (1.0f - nm);
        }
        out[0] = acc / ws[60];
    }
}

extern "C" void kernel_launch(void* const* d_in, const int* in_sizes, int n_in,
                              void* d_out, int out_size, void* d_ws, size_t ws_size,
                              hipStream_t stream) {
    const float* logit  = (const float*)d_in[0];
    const float* ema    = (const float*)d_in[1];
    const float* thresh = (const float*)d_in[2];
    const int*   real   = (const int*)d_in[3];
    const float* mpa    = (const float*)d_in[4];
    float* out = (float*)d_out;
    float* ws  = (float*)d_ws;

    // ws is re-poisoned to 0xAA before every timed launch; zero the 61 bins.
    hipMemsetAsync(ws, 0, 64 * sizeof(float), stream);

    dl_main<<<NBLK, 256, 0, stream>>>(logit, ema, thresh, real, ws);
    dl_final<<<1, 64, 0, stream>>>(ws, mpa, out);
}